// Round 1
// 570.892 us; speedup vs baseline: 1.0699x; 1.0699x over previous
//
#include <hip/hip_runtime.h>
#include <stdint.h>

#define TOK  4096
#define KIN  4096
#define NOUT 12288

#define BM  256
#define BN  256
#define BKB 128                 // K elements (= bytes) per K-tile
#define NKT (KIN / BKB)         // 32 K-tiles

typedef __attribute__((ext_vector_type(4))) int int32x4;

// ---------------------------------------------------------------------------
// Kernel 0: repack widened int32 weights -> packed int8 (unchanged).
// ---------------------------------------------------------------------------
__global__ __launch_bounds__(256) void repack_w(const int* __restrict__ w32,
                                                int8_t* __restrict__ w8)
{
    const size_t i = (size_t)blockIdx.x * 256 + threadIdx.x;   // int4 index
    const int4 v = ((const int4*)w32)[i];
    unsigned pack = ((unsigned)(uint8_t)(int8_t)v.x)
                  | ((unsigned)(uint8_t)(int8_t)v.y << 8)
                  | ((unsigned)(uint8_t)(int8_t)v.z << 16)
                  | ((unsigned)(uint8_t)(int8_t)v.w << 24);
    ((int*)w8)[i] = (int)pack;
}

// ---------------------------------------------------------------------------
// Kernel 1: per-token dynamic quantization (unchanged).
// ---------------------------------------------------------------------------
__global__ __launch_bounds__(256) void quant_rows(const float* __restrict__ x,
                                                  int8_t* __restrict__ xq,
                                                  float* __restrict__ ascale)
{
    const int row = blockIdx.x;
    const int tid = threadIdx.x;
    const float4* xr = (const float4*)(x + (size_t)row * KIN);

    float4 v[4];
    float m = 0.0f;
#pragma unroll
    for (int i = 0; i < 4; ++i) {
        v[i] = xr[tid + 256 * i];
        m = fmaxf(m, fmaxf(fmaxf(fabsf(v[i].x), fabsf(v[i].y)),
                           fmaxf(fabsf(v[i].z), fabsf(v[i].w))));
    }
#pragma unroll
    for (int off = 32; off > 0; off >>= 1)
        m = fmaxf(m, __shfl_down(m, off, 64));
    __shared__ float wm[4];
    if ((tid & 63) == 0) wm[tid >> 6] = m;
    __syncthreads();
    const float amax = fmaxf(fmaxf(wm[0], wm[1]), fmaxf(wm[2], wm[3]));
    const float s   = fmaxf(amax / 127.0f, 1e-8f);
    const float inv = 1.0f / s;
    if (tid == 0) ascale[row] = s;

    int* out32 = (int*)(xq + (size_t)row * KIN);
#pragma unroll
    for (int i = 0; i < 4; ++i) {
        float c[4] = {v[i].x, v[i].y, v[i].z, v[i].w};
        unsigned pack = 0;
#pragma unroll
        for (int j = 0; j < 4; ++j) {
            float r = rintf(c[j] * inv);
            r = fminf(fmaxf(r, -128.0f), 127.0f);
            pack |= ((unsigned)(uint8_t)(int8_t)(int)r) << (8 * j);
        }
        out32[tid + 256 * i] = (int)pack;
    }
}

// ---------------------------------------------------------------------------
// Kernel 2: int8 GEMM, 256x256 tile, BK=128, 8 waves, 8-phase counted-vmcnt
// schedule (m201 template ported to i8; T1 XCD swizzle + T2 XOR swizzle +
// T3/T4 8-phase counted vmcnt + T5 setprio).
//
// LDS: A[2 buf][256 rows][128 B]  (64 KiB), swizzle: chunk16 ^= (row & 7)
//      B[2 buf][2 k-plane][256 rows][64 B] (64 KiB), chunk16 ^= ((row>>1)&3)
// Swizzles applied on the pre-swizzled GLOBAL source (global_load_lds writes
// linearly) and on the ds_read address -- same involution both sides.
//
// Phases per K-tile (mh = wave M-half, ks = k-slice): (0,0) (1,0) (1,1) (0,1).
// Staging rhythm (one half-tile = 2 x global_load_lds, 8 KiB):
//   ph1: Ah0(T+1) + Bp1(T+1)  -> other buffer (4 loads)
//   ph2: --
//   ph3: Bp0(T+2) -> this buffer (its last read was ph2)
//   ph4: Ah1(T+2) -> this buffer (its last read was ph3); s_waitcnt vmcnt(4)
// Invariant: after each group-end vmcnt(4), next K-tile fully resident and
// exactly 2 half-tiles (4 loads) remain in flight. Tail groups clamp the
// k-offset (re-stage last tile's bytes into the dead buffer) -> no branches.
// ---------------------------------------------------------------------------
#define GLOAD_LDS16(g, l)                                                     \
    __builtin_amdgcn_global_load_lds(                                         \
        (const __attribute__((address_space(1))) unsigned int*)(g),           \
        (__attribute__((address_space(3))) unsigned int*)(l), 16, 0, 0)

#define STAGE_A(bufb, R0, kk)                                                 \
    GLOAD_LDS16(gA + (size_t)(R0) * KIN + (kk),                               \
                lA + (bufb) * 32768 + (R0) * 128)
#define STAGE_B(bufb, s, R0, kk)                                              \
    GLOAD_LDS16(gB + (size_t)(R0) * KIN + (kk) + (s) * 64,                    \
                lB + (bufb) * 32768 + (s) * 16384 + (R0) * 64)

#define PHASE(cur, mh, ks, STAGES, TAILWAIT)                                  \
    {                                                                         \
        const int abase = (cur) * 32768 + (mh) * 8192 + ((ks) ? aA1 : aA0);   \
        const int bbase = (cur) * 32768 + (ks) * 16384 + bA;                  \
        int32x4 af[4], bf[4];                                                 \
        _Pragma("unroll")                                                     \
        for (int u = 0; u < 4; ++u)                                           \
            af[u] = *(const int32x4*)(As + abase + u * 2048);                 \
        _Pragma("unroll")                                                     \
        for (int u = 0; u < 4; ++u)                                           \
            bf[u] = *(const int32x4*)(Bs + bbase + u * 1024);                 \
        STAGES;                                                               \
        __builtin_amdgcn_s_barrier();                                         \
        asm volatile("s_waitcnt lgkmcnt(0)" ::: "memory");                    \
        __builtin_amdgcn_sched_barrier(0);                                    \
        __builtin_amdgcn_s_setprio(1);                                        \
        _Pragma("unroll")                                                     \
        for (int fi = 0; fi < 4; ++fi)                                        \
            _Pragma("unroll")                                                 \
            for (int fj = 0; fj < 4; ++fj)                                    \
                acc[(mh) * 4 + fi][fj] =                                      \
                    __builtin_amdgcn_mfma_i32_16x16x64_i8(                    \
                        af[fi], bf[fj], acc[(mh) * 4 + fi][fj], 0, 0, 0);     \
        __builtin_amdgcn_s_setprio(0);                                        \
        TAILWAIT;                                                             \
        __builtin_amdgcn_s_barrier();                                         \
        asm volatile("" ::: "memory");                                        \
    }

__global__ __launch_bounds__(512, 2) void gemm_i8(const int8_t* __restrict__ A,
                                                  const int8_t* __restrict__ B,
                                                  const float* __restrict__ ascale,
                                                  const float* __restrict__ wscale,
                                                  const float* __restrict__ bias,
                                                  float* __restrict__ C)
{
    __shared__ __align__(16) int8_t As[2 * BM * BKB];        // 64 KiB
    __shared__ __align__(16) int8_t Bs[2 * 2 * BN * 64];     // 64 KiB

    const int tid  = (int)threadIdx.x;
    const int lane = tid & 63;
    const int wave = tid >> 6;
    const int quad = lane >> 4;
    const int l16  = lane & 15;
    const int wr   = wave >> 2;          // 0..1 (M)
    const int wc   = wave & 3;           // 0..3 (N)

    // XCD-aware swizzle: nwg = 768, 768 % 8 == 0 -> each XCD gets 96
    // consecutive tiles = 2 full by-rows (A panel L2-resident per XCD).
    const int nbx  = NOUT / BN;                       // 48
    const int wgid = (int)blockIdx.x;
    const int swz  = (wgid & 7) * (((TOK / BM) * nbx) >> 3) + (wgid >> 3);
    const int bx   = swz % nbx;
    const int by   = swz / nbx;
    const int m0   = by * BM;
    const int n0   = bx * BN;

    int32x4 acc[8][4];
#pragma unroll
    for (int i = 0; i < 8; ++i)
#pragma unroll
        for (int j = 0; j < 4; ++j) acc[i][j] = (int32x4){0, 0, 0, 0};

    // --- staging constants (per-thread, shared by all stage instructions) ---
    // A: slot t covers (row R0 + (t>>3), phys chunk t&7); logical = phys ^ (row&7)
    const int arow = tid >> 3;
    const int8_t* gA = A + (size_t)(m0 + arow) * KIN
                         + (((tid & 7) ^ (arow & 7)) << 4);
    // B plane: slot t covers (row R0 + (t>>2), phys chunk t&3); ^((row>>1)&3)
    const int brow = tid >> 2;
    const int8_t* gB = B + (size_t)(n0 + brow) * KIN
                         + ((((tid & 3) ^ ((tid >> 3) & 3))) << 4);
    int8_t* lA = As + tid * 16;
    int8_t* lB = Bs + tid * 16;

    // --- reader constants (row&7 == l16&7; (row>>1)&3 == (l16>>1)&3) ---
    const int aA0 = (wr * 128 + l16) * 128 + (((0 + quad) ^ (l16 & 7)) << 4);
    const int aA1 = (wr * 128 + l16) * 128 + (((4 + quad) ^ (l16 & 7)) << 4);
    const int bA  = (wc * 64 + l16) * 64 + ((quad ^ ((l16 >> 1) & 3)) << 4);

    // --- prologue: T0 (all 4 halves) + Bp0,Ah1 of T1; leave 4 loads in flight
    STAGE_A(0, 0, 0);      STAGE_A(0, 128, 0);       // Ah0(T0)
    STAGE_A(0, 64, 0);     STAGE_A(0, 192, 0);       // Ah1(T0)
    STAGE_B(0, 0, 0, 0);   STAGE_B(0, 0, 128, 0);    // Bp0(T0)
    STAGE_B(0, 1, 0, 0);   STAGE_B(0, 1, 128, 0);    // Bp1(T0)
    STAGE_B(1, 0, 0, BKB); STAGE_B(1, 0, 128, BKB);  // Bp0(T1)
    STAGE_A(1, 64, BKB);   STAGE_A(1, 192, BKB);     // Ah1(T1)
    asm volatile("s_waitcnt vmcnt(4)" ::: "memory");
    __builtin_amdgcn_s_barrier();
    asm volatile("" ::: "memory");

#pragma unroll 1
    for (int g = 0; g < NKT; g += 2) {
        const int k1 = (g + 1) * BKB;
        const int k2 = (g + 2 < NKT ? g + 2 : NKT - 1) * BKB;
        const int k3 = (g + 3 < NKT ? g + 3 : NKT - 1) * BKB;
        // ---- even group: computes tile g from buf0, nxt = buf1
        PHASE(0, 0, 0, { STAGE_A(1, 0, k1);    STAGE_A(1, 128, k1);
                         STAGE_B(1, 1, 0, k1); STAGE_B(1, 1, 128, k1); }, )
        PHASE(0, 1, 0, , )
        PHASE(0, 1, 1, { STAGE_B(0, 0, 0, k2); STAGE_B(0, 0, 128, k2); }, )
        PHASE(0, 0, 1, { STAGE_A(0, 64, k2);   STAGE_A(0, 192, k2); },
              asm volatile("s_waitcnt vmcnt(4)" ::: "memory"))
        // ---- odd group: computes tile g+1 from buf1, nxt = buf0
        PHASE(1, 0, 0, { STAGE_A(0, 0, k2);    STAGE_A(0, 128, k2);
                         STAGE_B(0, 1, 0, k2); STAGE_B(0, 1, 128, k2); }, )
        PHASE(1, 1, 0, , )
        PHASE(1, 1, 1, { STAGE_B(1, 0, 0, k3); STAGE_B(1, 0, 128, k3); }, )
        PHASE(1, 0, 1, { STAGE_A(1, 64, k3);   STAGE_A(1, 192, k3); },
              asm volatile("s_waitcnt vmcnt(4)" ::: "memory"))
    }

    // --- epilogue: C/D layout col = l16, row = quad*4 + reg ---
#pragma unroll
    for (int fi = 0; fi < 8; ++fi) {
        const int mb = m0 + wr * 128 + fi * 16 + quad * 4;
        const float as0 = ascale[mb + 0];
        const float as1 = ascale[mb + 1];
        const float as2 = ascale[mb + 2];
        const float as3 = ascale[mb + 3];
#pragma unroll
        for (int fj = 0; fj < 4; ++fj) {
            const int n = n0 + wc * 64 + fj * 16 + l16;
            const float wsn = wscale[n];
            const float bn  = bias[n];
            float* Cp = C + (size_t)mb * NOUT + n;
            Cp[0 * (size_t)NOUT] = (float)acc[fi][fj][0] * as0 * wsn + bn;
            Cp[1 * (size_t)NOUT] = (float)acc[fi][fj][1] * as1 * wsn + bn;
            Cp[2 * (size_t)NOUT] = (float)acc[fi][fj][2] * as2 * wsn + bn;
            Cp[3 * (size_t)NOUT] = (float)acc[fi][fj][3] * as3 * wsn + bn;
        }
    }
}

extern "C" void kernel_launch(void* const* d_in, const int* in_sizes, int n_in,
                              void* d_out, int out_size, void* d_ws, size_t ws_size,
                              hipStream_t stream)
{
    (void)in_sizes; (void)n_in; (void)out_size; (void)ws_size;
    const float* x      = (const float*)d_in[0];
    const int*   w32    = (const int*)d_in[1];      // int8 widened to int32
    const float* wscale = (const float*)d_in[2];
    const float* bias   = (const float*)d_in[3];
    float*       out    = (float*)d_out;

    int8_t* xq     = (int8_t*)d_ws;                               // 16 MiB
    float*  ascale = (float*)((char*)d_ws + (size_t)TOK * KIN);   // 16 KiB
    int8_t* w8     = (int8_t*)((char*)d_ws + (size_t)TOK * KIN + 65536);

    repack_w<<<(size_t)NOUT * KIN / 4 / 256, 256, 0, stream>>>(w32, w8);
    quant_rows<<<TOK, 256, 0, stream>>>(x, xq, ascale);
    gemm_i8<<<(TOK / BM) * (NOUT / BN), 512, 0, stream>>>(xq, w8, ascale,
                                                          wscale, bias, out);
}

// Round 2
// 566.579 us; speedup vs baseline: 1.0780x; 1.0076x over previous
//
#include <hip/hip_runtime.h>
#include <stdint.h>

#define TOK  4096
#define KIN  4096
#define NOUT 12288

#define BM  256
#define BN  256
#define BKB 128                 // K elements (= bytes) per K-tile
#define NKT (KIN / BKB)         // 32 K-tiles

typedef __attribute__((ext_vector_type(4)))  int int32x4;
typedef __attribute__((ext_vector_type(16))) int int32x16;

// ---------------------------------------------------------------------------
// Kernel 0: repack widened int32 weights -> packed int8 (unchanged).
// ---------------------------------------------------------------------------
__global__ __launch_bounds__(256) void repack_w(const int* __restrict__ w32,
                                                int8_t* __restrict__ w8)
{
    const size_t i = (size_t)blockIdx.x * 256 + threadIdx.x;   // int4 index
    const int4 v = ((const int4*)w32)[i];
    unsigned pack = ((unsigned)(uint8_t)(int8_t)v.x)
                  | ((unsigned)(uint8_t)(int8_t)v.y << 8)
                  | ((unsigned)(uint8_t)(int8_t)v.z << 16)
                  | ((unsigned)(uint8_t)(int8_t)v.w << 24);
    ((int*)w8)[i] = (int)pack;
}

// ---------------------------------------------------------------------------
// Kernel 1: per-token dynamic quantization (unchanged).
// ---------------------------------------------------------------------------
__global__ __launch_bounds__(256) void quant_rows(const float* __restrict__ x,
                                                  int8_t* __restrict__ xq,
                                                  float* __restrict__ ascale)
{
    const int row = blockIdx.x;
    const int tid = threadIdx.x;
    const float4* xr = (const float4*)(x + (size_t)row * KIN);

    float4 v[4];
    float m = 0.0f;
#pragma unroll
    for (int i = 0; i < 4; ++i) {
        v[i] = xr[tid + 256 * i];
        m = fmaxf(m, fmaxf(fmaxf(fabsf(v[i].x), fabsf(v[i].y)),
                           fmaxf(fabsf(v[i].z), fabsf(v[i].w))));
    }
#pragma unroll
    for (int off = 32; off > 0; off >>= 1)
        m = fmaxf(m, __shfl_down(m, off, 64));
    __shared__ float wm[4];
    if ((tid & 63) == 0) wm[tid >> 6] = m;
    __syncthreads();
    const float amax = fmaxf(fmaxf(wm[0], wm[1]), fmaxf(wm[2], wm[3]));
    const float s   = fmaxf(amax / 127.0f, 1e-8f);
    const float inv = 1.0f / s;
    if (tid == 0) ascale[row] = s;

    int* out32 = (int*)(xq + (size_t)row * KIN);
#pragma unroll
    for (int i = 0; i < 4; ++i) {
        float c[4] = {v[i].x, v[i].y, v[i].z, v[i].w};
        unsigned pack = 0;
#pragma unroll
        for (int j = 0; j < 4; ++j) {
            float r = rintf(c[j] * inv);
            r = fminf(fmaxf(r, -128.0f), 127.0f);
            pack |= ((unsigned)(uint8_t)(int8_t)(int)r) << (8 * j);
        }
        out32[tid + 256 * i] = (int)pack;
    }
}

// ---------------------------------------------------------------------------
// Kernel 2: int8 GEMM, 256x256 tile, BK=128, 8 waves, 8-phase counted-vmcnt.
// R2 changes vs R1:
//  (a) 32x32x32 i8 MFMA (2x ops per fragment byte, faster pipe, half the
//      mfma instruction count). acc[4][2] x int32x16 = same 128 acc regs.
//  (b) B-fragments held in registers across same-ks phase pairs
//      ((0,0)(1,0) and (1,1)(0,1)) -> LDS read/phase 64KB -> 48KB avg.
//  (c) NO lgkmcnt(0)/sched_barrier(0) drain before the MFMA cluster: plain
//      C++ ds_reads -> compiler emits fine-grained lgkmcnt(N) per use, so
//      MFMA overlaps remaining LDS returns (this was ~380 cyc/phase of
//      serialization in R1). Raw s_barrier + asm memory clobbers keep
//      compiler-level ordering; counted vmcnt(4) unchanged (R1-verified).
//
// LDS image + staging + swizzles byte-identical to R1 (0 bank conflicts):
//   A[2][256][128], chunk16 ^= (row&7); B[2][2 ksplane][256][64],
//   chunk16 ^= ((row>>1)&3). gload_lds dest linear; global source
//   pre-swizzled (rule 21).
//
// 32x32x32 i8 fragment mapping (extension of verified 16x16x64 pattern):
//   A/B: lane l holds row l&31, k-bytes (l>>5)*16 + [0,16)
//   C/D: col = lane&31 (n), row = (reg&3) + 8*(reg>>2) + 4*(lane>>5) (m)
// ---------------------------------------------------------------------------
#define GLOAD_LDS16(g, l)                                                     \
    __builtin_amdgcn_global_load_lds(                                         \
        (const __attribute__((address_space(1))) unsigned int*)(g),           \
        (__attribute__((address_space(3))) unsigned int*)(l), 16, 0, 0)

#define STAGE_A(bufb, R0, kk)                                                 \
    GLOAD_LDS16(gA + (size_t)(R0) * KIN + (kk),                               \
                lA + (bufb) * 32768 + (R0) * 128)
#define STAGE_B(bufb, s, R0, kk)                                              \
    GLOAD_LDS16(gB + (size_t)(R0) * KIN + (kk) + (s) * 64,                    \
                lB + (bufb) * 32768 + (s) * 16384 + (R0) * 64)

// af[kst*2+rb], bf[kst*2+cb]
#define LOAD_AF(cur, mh, ks)                                                  \
    af[0] = *(const int32x4*)(aP[(ks)*2+0] + (cur)*32768 + ((mh)*64+ 0)*128); \
    af[1] = *(const int32x4*)(aP[(ks)*2+0] + (cur)*32768 + ((mh)*64+32)*128); \
    af[2] = *(const int32x4*)(aP[(ks)*2+1] + (cur)*32768 + ((mh)*64+ 0)*128); \
    af[3] = *(const int32x4*)(aP[(ks)*2+1] + (cur)*32768 + ((mh)*64+32)*128);

#define LOAD_BF(cur, ks)                                                      \
    bf[0] = *(const int32x4*)(bP[0] + (cur)*32768 + (ks)*16384 +    0);       \
    bf[1] = *(const int32x4*)(bP[0] + (cur)*32768 + (ks)*16384 + 2048);       \
    bf[2] = *(const int32x4*)(bP[1] + (cur)*32768 + (ks)*16384 +    0);       \
    bf[3] = *(const int32x4*)(bP[1] + (cur)*32768 + (ks)*16384 + 2048);

#define MFMA32(a, b, c) __builtin_amdgcn_mfma_i32_32x32x32_i8((a), (b), (c), 0, 0, 0)

#define DO_MFMA(mh)                                                           \
    acc[(mh)*2+0][0] = MFMA32(af[0], bf[0], acc[(mh)*2+0][0]);                \
    acc[(mh)*2+0][1] = MFMA32(af[0], bf[1], acc[(mh)*2+0][1]);                \
    acc[(mh)*2+1][0] = MFMA32(af[1], bf[0], acc[(mh)*2+1][0]);                \
    acc[(mh)*2+1][1] = MFMA32(af[1], bf[1], acc[(mh)*2+1][1]);                \
    acc[(mh)*2+0][0] = MFMA32(af[2], bf[2], acc[(mh)*2+0][0]);                \
    acc[(mh)*2+0][1] = MFMA32(af[2], bf[3], acc[(mh)*2+0][1]);                \
    acc[(mh)*2+1][0] = MFMA32(af[3], bf[2], acc[(mh)*2+1][0]);                \
    acc[(mh)*2+1][1] = MFMA32(af[3], bf[3], acc[(mh)*2+1][1]);

#define PHASE(cur, mh, ks, LOADBF, STAGES, TAILWAIT)                          \
    {                                                                         \
        LOADBF;                                                               \
        LOAD_AF(cur, mh, ks);                                                 \
        STAGES;                                                               \
        asm volatile("" ::: "memory");                                        \
        __builtin_amdgcn_s_barrier();                                         \
        asm volatile("" ::: "memory");                                        \
        __builtin_amdgcn_s_setprio(1);                                        \
        DO_MFMA(mh);                                                          \
        __builtin_amdgcn_s_setprio(0);                                        \
        TAILWAIT;                                                             \
        asm volatile("" ::: "memory");                                        \
        __builtin_amdgcn_s_barrier();                                         \
        asm volatile("" ::: "memory");                                        \
    }

__global__ __launch_bounds__(512, 2) void gemm_i8(const int8_t* __restrict__ A,
                                                  const int8_t* __restrict__ B,
                                                  const float* __restrict__ ascale,
                                                  const float* __restrict__ wscale,
                                                  const float* __restrict__ bias,
                                                  float* __restrict__ C)
{
    __shared__ __align__(16) int8_t As[2 * BM * BKB];        // 64 KiB
    __shared__ __align__(16) int8_t Bs[2 * 2 * BN * 64];     // 64 KiB

    const int tid  = (int)threadIdx.x;
    const int lane = tid & 63;
    const int wave = tid >> 6;
    const int hi   = lane >> 5;          // k-group within fragment
    const int l5   = lane & 31;          // row within 32-row block
    const int wr   = wave >> 2;          // 0..1 (M)
    const int wc   = wave & 3;           // 0..3 (N)

    // XCD-aware swizzle (768 wgs, 768 % 8 == 0 -> bijective)
    const int nbx  = NOUT / BN;                       // 48
    const int wgid = (int)blockIdx.x;
    const int swz  = (wgid & 7) * (((TOK / BM) * nbx) >> 3) + (wgid >> 3);
    const int bx   = swz % nbx;
    const int by   = swz / nbx;
    const int m0   = by * BM;
    const int n0   = bx * BN;

    const int32x16 zero = {0,0,0,0,0,0,0,0,0,0,0,0,0,0,0,0};
    int32x16 acc[4][2];
#pragma unroll
    for (int i = 0; i < 4; ++i) { acc[i][0] = zero; acc[i][1] = zero; }

    // --- staging constants (identical to R1) ---
    const int arow = tid >> 3;
    const int8_t* gA = A + (size_t)(m0 + arow) * KIN
                         + (((tid & 7) ^ (arow & 7)) << 4);
    const int brow = tid >> 2;
    const int8_t* gB = B + (size_t)(n0 + brow) * KIN
                         + ((((tid & 3) ^ ((tid >> 3) & 3))) << 4);
    int8_t* lA = As + tid * 16;
    int8_t* lB = Bs + tid * 16;

    // --- reader fragment pointers ---
    // A logical chunk c = ks*4 + kstep*2 + hi ; phys = c ^ (row&7), row&7 = l5&7
    const int8_t* aP[4];
#pragma unroll
    for (int i = 0; i < 4; ++i)
        aP[i] = As + (wr * 128 + l5) * 128 + (((i * 2 + hi) ^ (l5 & 7)) << 4);
    // B logical chunk c = kstep*2 + hi ; phys = c ^ ((row>>1)&3)
    const int8_t* bP[2];
#pragma unroll
    for (int i = 0; i < 2; ++i)
        bP[i] = Bs + (wc * 64 + l5) * 64 + (((i * 2 + hi) ^ ((l5 >> 1) & 3)) << 4);

    int32x4 af[4], bf[4];

    // --- prologue: T0 full + Bp0,Ah1 of T1; leave exactly 4 loads in flight
    STAGE_A(0, 0, 0);      STAGE_A(0, 128, 0);       // Ah0(T0)
    STAGE_A(0, 64, 0);     STAGE_A(0, 192, 0);       // Ah1(T0)
    STAGE_B(0, 0, 0, 0);   STAGE_B(0, 0, 128, 0);    // Bp0(T0)
    STAGE_B(0, 1, 0, 0);   STAGE_B(0, 1, 128, 0);    // Bp1(T0)
    STAGE_B(1, 0, 0, BKB); STAGE_B(1, 0, 128, BKB);  // Bp0(T1)
    STAGE_A(1, 64, BKB);   STAGE_A(1, 192, BKB);     // Ah1(T1)
    asm volatile("s_waitcnt vmcnt(4)" ::: "memory");
    __builtin_amdgcn_s_barrier();
    asm volatile("" ::: "memory");

#pragma unroll 1
    for (int g = 0; g < NKT; g += 2) {
        const int k1 = (g + 1) * BKB;
        const int k2 = (g + 2 < NKT ? g + 2 : NKT - 1) * BKB;
        const int k3 = (g + 3 < NKT ? g + 3 : NKT - 1) * BKB;
        // ---- even group: tile g from buf0, nxt = buf1
        PHASE(0, 0, 0, LOAD_BF(0, 0),
              { STAGE_A(1, 0, k1);    STAGE_A(1, 128, k1); }, )
        PHASE(0, 1, 0, ,
              { STAGE_B(1, 1, 0, k1); STAGE_B(1, 1, 128, k1); }, )
        PHASE(0, 1, 1, LOAD_BF(0, 1),
              { STAGE_B(0, 0, 0, k2); STAGE_B(0, 0, 128, k2); }, )
        PHASE(0, 0, 1, ,
              { STAGE_A(0, 64, k2);   STAGE_A(0, 192, k2); },
              asm volatile("s_waitcnt vmcnt(4)" ::: "memory"))
        // ---- odd group: tile g+1 from buf1, nxt = buf0
        PHASE(1, 0, 0, LOAD_BF(1, 0),
              { STAGE_A(0, 0, k2);    STAGE_A(0, 128, k2); }, )
        PHASE(1, 1, 0, ,
              { STAGE_B(0, 1, 0, k2); STAGE_B(0, 1, 128, k2); }, )
        PHASE(1, 1, 1, LOAD_BF(1, 1),
              { STAGE_B(1, 0, 0, k3); STAGE_B(1, 0, 128, k3); }, )
        PHASE(1, 0, 1, ,
              { STAGE_A(1, 64, k3);   STAGE_A(1, 192, k3); },
              asm volatile("s_waitcnt vmcnt(4)" ::: "memory"))
    }

    // --- epilogue: C/D col = l5 (n), row = (reg&3) + 8*(reg>>2) + 4*hi (m)
    const int nn0 = n0 + wc * 64 + l5;
    const float wsn0 = wscale[nn0],      bn0 = bias[nn0];
    const float wsn1 = wscale[nn0 + 32], bn1 = bias[nn0 + 32];
#pragma unroll
    for (int R = 0; R < 4; ++R) {
#pragma unroll
        for (int rq = 0; rq < 4; ++rq) {
            const int mb = m0 + wr * 128 + R * 32 + rq * 8 + hi * 4;
            const float a0 = ascale[mb + 0];
            const float a1 = ascale[mb + 1];
            const float a2 = ascale[mb + 2];
            const float a3 = ascale[mb + 3];
            float* Cp = C + (size_t)mb * NOUT + nn0;
            Cp[0 * (size_t)NOUT]      = (float)acc[R][0][rq*4+0] * a0 * wsn0 + bn0;
            Cp[1 * (size_t)NOUT]      = (float)acc[R][0][rq*4+1] * a1 * wsn0 + bn0;
            Cp[2 * (size_t)NOUT]      = (float)acc[R][0][rq*4+2] * a2 * wsn0 + bn0;
            Cp[3 * (size_t)NOUT]      = (float)acc[R][0][rq*4+3] * a3 * wsn0 + bn0;
            Cp[0 * (size_t)NOUT + 32] = (float)acc[R][1][rq*4+0] * a0 * wsn1 + bn1;
            Cp[1 * (size_t)NOUT + 32] = (float)acc[R][1][rq*4+1] * a1 * wsn1 + bn1;
            Cp[2 * (size_t)NOUT + 32] = (float)acc[R][1][rq*4+2] * a2 * wsn1 + bn1;
            Cp[3 * (size_t)NOUT + 32] = (float)acc[R][1][rq*4+3] * a3 * wsn1 + bn1;
        }
    }
}

extern "C" void kernel_launch(void* const* d_in, const int* in_sizes, int n_in,
                              void* d_out, int out_size, void* d_ws, size_t ws_size,
                              hipStream_t stream)
{
    (void)in_sizes; (void)n_in; (void)out_size; (void)ws_size;
    const float* x      = (const float*)d_in[0];
    const int*   w32    = (const int*)d_in[1];      // int8 widened to int32
    const float* wscale = (const float*)d_in[2];
    const float* bias   = (const float*)d_in[3];
    float*       out    = (float*)d_out;

    int8_t* xq     = (int8_t*)d_ws;                               // 16 MiB
    float*  ascale = (float*)((char*)d_ws + (size_t)TOK * KIN);   // 16 KiB
    int8_t* w8     = (int8_t*)((char*)d_ws + (size_t)TOK * KIN + 65536);

    repack_w<<<(size_t)NOUT * KIN / 4 / 256, 256, 0, stream>>>(w32, w8);
    quant_rows<<<TOK, 256, 0, stream>>>(x, xq, ascale);
    gemm_i8<<<(TOK / BM) * (NOUT / BN), 512, 0, stream>>>(xq, w8, ascale,
                                                          wscale, bias, out);
}